// Round 7
// baseline (203.702 us; speedup 1.0000x reference)
//
#include <hip/hip_runtime.h>
#include <hip/hip_bf16.h>
#include <math.h>

#define D_MODEL 1024
#define NHEAD 16
#define DHEAD 64
#define SEQ 2048
#define BATCH 2
#define MTOT (BATCH * SEQ)  // 4096

typedef __attribute__((ext_vector_type(8))) short bf16x8;   // 4 VGPRs = MFMA A/B frag
typedef __attribute__((ext_vector_type(4))) float f32x4;    // MFMA C/D frag

static __device__ __forceinline__ ushort f2b(float x) {
  __hip_bfloat16 h = __float2bfloat16(x);
  union { __hip_bfloat16 h; ushort u; } cv; cv.h = h; return cv.u;
}

// async global->LDS, 16B per lane (m97). LDS dest = wave-uniform base + lane*16.
#define GLLDS16(gp, lp)                                                     \
  __builtin_amdgcn_global_load_lds(                                         \
      (const __attribute__((address_space(1))) unsigned int*)(gp),          \
      (__attribute__((address_space(3))) unsigned int*)(lp), 16, 0, 0)

// 0.125 (1/sqrt(Dh)) * log2(e): folded into Q at projection; flash exp2's raw scores
#define QSCALE 0.18033688011112042f

// ---------------------------------------------------------------------------
// prep: fp32->bf16 for X + 4 weights, plus RoPE cos/sin table (2048 x 32
// float2, 512 KB -> L2-resident for the gemm epilogue).
// blocks [0,4096): X ; [4096,8192): weights ; [8192,8448): table.
// ---------------------------------------------------------------------------
__global__ __launch_bounds__(256)
void prep(const float* __restrict__ X, const float* __restrict__ Wq,
          const float* __restrict__ Wk, const float* __restrict__ Wv,
          const float* __restrict__ Wo, ushort* __restrict__ Xb,
          ushort* __restrict__ Wqb, ushort* __restrict__ Wkb,
          ushort* __restrict__ Wvb, ushort* __restrict__ Wob,
          float2* __restrict__ tbl) {
  int bid = blockIdx.x;
  if (bid >= 8192) {  // rope table: idx = s*32 + i
    int idx = (bid - 8192) * 256 + threadIdx.x;
    int s = idx >> 5, i = idx & 31;
    float inv = exp2f((float)i * -0.4152410118609203f);  // 10000^(-i/32)
    float sn, cs;
    sincosf((float)s * inv, &sn, &cs);
    tbl[idx] = make_float2(cs, sn);
    return;
  }
  const float* in;
  ushort* out;
  int i;
  if (bid < 4096) {
    in = X; out = Xb; i = bid * 256 + threadIdx.x;
  } else {
    int ws = (bid - 4096) >> 10;
    in = (ws == 0) ? Wq : (ws == 1) ? Wk : (ws == 2) ? Wv : Wo;
    out = (ws == 0) ? Wqb : (ws == 1) ? Wkb : (ws == 2) ? Wvb : Wob;
    i = ((bid - 4096) & 1023) * 256 + threadIdx.x;
  }
  float4 v = ((const float4*)in)[i];
  ushort4 o;
  o.x = f2b(v.x); o.y = f2b(v.y); o.z = f2b(v.z); o.w = f2b(v.w);
  ((ushort4*)out)[i] = o;
}

// ---------------------------------------------------------------------------
// bf16 MFMA GEMM, single-barrier double-buffered GLLDS staging:
//   prologue: GLLDS(tile 0)->buf0
//   iter kt : barrier (drains prefetch of kt) -> issue GLLDS(kt+1)->buf^1
//             -> frag reads + MFMA on buf  [prefetch overlaps compute]
// WAR safe: reads of buf^1 (iter kt-1) completed before the barrier that
// precedes the writes. Chunk swizzle f(row)=((row>>2)^row)&3: staging thread
// (row r0, slot c) holds global chunk c^f(r0); reader slot quad^f(row) ->
// conflict-free ds_read_b128 (verified: SQ_LDS_BANK_CONFLICT=0, R6).
// mode 1 (QKV, z = 0/1/2 = Q/K/V): RoPE-by-table on Q/K (+QSCALE on Q),
// V written directly transposed (B,H,Dh,S). mode 0: fp32 row-major out.
// ---------------------------------------------------------------------------
__global__ __launch_bounds__(256)
void gemm_bf16(const ushort* __restrict__ A,
               const ushort* __restrict__ W0, const ushort* __restrict__ W1,
               const ushort* __restrict__ W2,
               const float2* __restrict__ tbl,
               float* __restrict__ outF,
               ushort* __restrict__ o0, ushort* __restrict__ o1,
               ushort* __restrict__ o2, int mode) {
  __shared__ ushort As[2][128 * 32];
  __shared__ ushort Bs[2][128 * 32];
  const int tid = threadIdx.x;
  const int lane = tid & 63;
  const int w = tid >> 6;
  const int quad = lane >> 4, l15 = lane & 15;
  const int wy = w >> 1, wx = w & 1;
  const int m0 = blockIdx.y * 128, n0 = blockIdx.x * 128;
  const int z = blockIdx.z;
  const ushort* W = (z == 0) ? W0 : (z == 1) ? W1 : W2;
  ushort* outB = (z == 0) ? o0 : (z == 1) ? o1 : o2;

  // staging: thread t owns slots t and t+256 (rows r0, r0+64; same chunk)
  const int r0 = tid >> 2, c0 = tid & 3;
  const int gc = c0 ^ (((r0 >> 2) ^ r0) & 3);  // f(r0) == f(r0+64)
  const ushort* Ag0 = A + (size_t)(m0 + r0) * D_MODEL + gc * 8;
  const ushort* Ag1 = A + (size_t)(m0 + r0 + 64) * D_MODEL + gc * 8;
  const ushort* Wg0 = W + (size_t)(n0 + r0) * D_MODEL + gc * 8;
  const ushort* Wg1 = W + (size_t)(n0 + r0 + 64) * D_MODEL + gc * 8;

  // reader chunk slot: f(row) = ((l15>>2) ^ l15) & 3 (mt/wy parts ≡ 0 mod 4)
  const int sw = (quad ^ (l15 >> 2) ^ l15) & 3;

  f32x4 acc[4][4];
#pragma unroll
  for (int i = 0; i < 4; ++i)
#pragma unroll
    for (int j = 0; j < 4; ++j) acc[i][j] = (f32x4){0.f, 0.f, 0.f, 0.f};

  // prologue: prefetch tile 0 into buf 0
  GLLDS16(Ag0, &As[0][tid * 8]);
  GLLDS16(Ag1, &As[0][(tid + 256) * 8]);
  GLLDS16(Wg0, &Bs[0][tid * 8]);
  GLLDS16(Wg1, &Bs[0][(tid + 256) * 8]);

  for (int kt = 0; kt < D_MODEL / 32; ++kt) {
    __syncthreads();  // drains GLLDS(kt); also fences prev iter's ds_reads
    const int cur = kt & 1, nxt = cur ^ 1;
    if (kt + 1 < D_MODEL / 32) {  // prefetch kt+1; overlaps MFMA below
      GLLDS16(Ag0 + (kt + 1) * 32, &As[nxt][tid * 8]);
      GLLDS16(Ag1 + (kt + 1) * 32, &As[nxt][(tid + 256) * 8]);
      GLLDS16(Wg0 + (kt + 1) * 32, &Bs[nxt][tid * 8]);
      GLLDS16(Wg1 + (kt + 1) * 32, &Bs[nxt][(tid + 256) * 8]);
    }

    bf16x8 af[4], bfr[4];
#pragma unroll
    for (int mt = 0; mt < 4; ++mt) {
      int row = wy * 64 + mt * 16 + l15;
      af[mt] = *(const bf16x8*)&As[cur][(row * 4 + sw) * 8];
    }
#pragma unroll
    for (int nt = 0; nt < 4; ++nt) {
      int row = wx * 64 + nt * 16 + l15;
      bfr[nt] = *(const bf16x8*)&Bs[cur][(row * 4 + sw) * 8];
    }
#pragma unroll
    for (int mt = 0; mt < 4; ++mt)
#pragma unroll
      for (int nt = 0; nt < 4; ++nt)
        acc[mt][nt] = __builtin_amdgcn_mfma_f32_16x16x32_bf16(
            af[mt], bfr[nt], acc[mt][nt], 0, 0, 0);
  }

  // ---- epilogue. C/D: row = quad*4+r, col = l15 per 16x16 tile.
  const float qsc = (z == 0) ? QSCALE : 1.0f;
#pragma unroll
  for (int mt = 0; mt < 4; ++mt) {
    int m_base = m0 + wy * 64 + mt * 16 + quad * 4;
    int b = m_base >> 11, s_base = m_base & (SEQ - 1);
#pragma unroll
    for (int nt = 0; nt < 4; ++nt) {
      int n = n0 + wx * 64 + nt * 16 + l15;
      if (mode == 0) {
#pragma unroll
        for (int r = 0; r < 4; ++r)
          outF[(size_t)(m_base + r) * D_MODEL + n] = acc[mt][nt][r];
      } else {
        int h = n >> 6, dh = n & 63;
        if (z == 2) {  // V: transposed store, 4 consecutive s in one ushort4
          ushort4 o;
          o.x = f2b(acc[mt][nt][0]); o.y = f2b(acc[mt][nt][1]);
          o.z = f2b(acc[mt][nt][2]); o.w = f2b(acc[mt][nt][3]);
          *(ushort4*)&outB[((size_t)(b * NHEAD + h) * DHEAD + dh) * SEQ + s_base] = o;
        } else {       // Q/K: RoPE via table, pair partner via lane shuffle
          int i = nt * 8 + (l15 >> 1);   // freq index, pair-uniform
          bool evn = !(l15 & 1);
#pragma unroll
          for (int r = 0; r < 4; ++r) {
            float v = acc[mt][nt][r];
            float pv = __shfl_xor(v, 1);
            float2 csn = tbl[(s_base + r) * 32 + i];
            v = v * csn.x + (evn ? -pv * csn.y : pv * csn.y);
            v *= qsc;
            outB[(((size_t)(b * NHEAD + h)) * SEQ + s_base + r) * DHEAD + dh] = f2b(v);
          }
        }
      }
    }
  }
}

// ---------------------------------------------------------------------------
// bf16 MFMA causal flash attention, no-max-shift softmax (scores bounded;
// Q pre-scaled by QSCALE at projection so exp2 applies directly).
// Single-barrier double-buffered GLLDS staging (same pattern as gemm):
// GLLDS(kt+1) issued right after the barrier, overlapping the whole tile-kt
// compute; the next iteration's barrier drains it. K/V in UNPADDED [64][64]
// tiles, source-XOR chunk swizzle (slot c^(r&7); readers quad^(l15&7)):
// conflict-free (R6: SQ_LDS_BANK_CONFLICT=0). Ps stride 68: 2-way (free).
// Per-lane partial row sums, one shuffle-reduce in epilogue. Heads 8-15
// walk qt reversed to balance ktiles across CUs.
// ---------------------------------------------------------------------------
__global__ __launch_bounds__(256)
void flash_mfma(const ushort* __restrict__ Q, const ushort* __restrict__ K,
                const ushort* __restrict__ Vt, ushort* __restrict__ O) {
  __shared__ ushort Ks[2][64 * 64];  // [key][dh], chunk-swizzled
  __shared__ ushort Vs[2][64 * 64];  // [dh][key], chunk-swizzled
  __shared__ ushort Ps[4][16][68];   // per-wave P: [qrow][key]
  const int tid = threadIdx.x;
  const int lane = tid & 63, w = tid >> 6;
  const int quad = lane >> 4, l15 = lane & 15;
  const int h = blockIdx.y, b = blockIdx.z;
  const int qt = (h >= 8) ? (31 - blockIdx.x) : blockIdx.x;
  const int bh = b * NHEAD + h;

  const ushort* Qrow = Q + ((size_t)bh * SEQ + qt * 64 + w * 16 + l15) * 64;
  bf16x8 aq0 = *(const bf16x8*)(Qrow + quad * 8);
  bf16x8 aq1 = *(const bf16x8*)(Qrow + 32 + quad * 8);

  const int rl = tid >> 3;
  const int gsc = (tid & 7) ^ (rl & 7);
  const ushort* Kg  = K  + ((size_t)bh * SEQ + rl) * 64 + gsc * 8;
  const ushort* Kg2 = Kg + (size_t)32 * 64;
  const ushort* Vg  = Vt + ((size_t)bh * 64 + rl) * SEQ + gsc * 8;
  const ushort* Vg2 = Vg + (size_t)32 * SEQ;

  const int sA = (quad ^ (l15 & 7)) * 8;  // k/keys 0..31
  const int sB = sA ^ 32;                 // k/keys 32..63

  float rsl[4];
  f32x4 accO[4];
#pragma unroll
  for (int r = 0; r < 4; ++r) rsl[r] = 0.f;
#pragma unroll
  for (int nt = 0; nt < 4; ++nt) accO[nt] = (f32x4){0.f, 0.f, 0.f, 0.f};

  const int qrow0 = qt * 64 + w * 16 + quad * 4;

  // prologue: prefetch tile 0 into buf 0
  GLLDS16(Kg,  &Ks[0][tid * 8]);
  GLLDS16(Kg2, &Ks[0][2048 + tid * 8]);
  GLLDS16(Vg,  &Vs[0][tid * 8]);
  GLLDS16(Vg2, &Vs[0][2048 + tid * 8]);

  for (int kt = 0; kt <= qt; ++kt) {
    __syncthreads();  // drains GLLDS(kt); fences prev iter's ds_reads
    const int cur = kt & 1, nxt = cur ^ 1;
    if (kt < qt) {    // prefetch kt+1; overlaps all of tile-kt compute
      GLLDS16(Kg  + (size_t)(kt + 1) * 64 * 64, &Ks[nxt][tid * 8]);
      GLLDS16(Kg2 + (size_t)(kt + 1) * 64 * 64, &Ks[nxt][2048 + tid * 8]);
      GLLDS16(Vg  + (kt + 1) * 64,              &Vs[nxt][tid * 8]);
      GLLDS16(Vg2 + (kt + 1) * 64,              &Vs[nxt][2048 + tid * 8]);
    }

    // ---- scores = Q . K^T (exp2 units)
    f32x4 sc[4];
#pragma unroll
    for (int nt = 0; nt < 4; ++nt) {
      const ushort* kr = &Ks[cur][(nt * 16 + l15) * 64];
      bf16x8 bk0 = *(const bf16x8*)(kr + sA);
      bf16x8 bk1 = *(const bf16x8*)(kr + sB);
      f32x4 zz = (f32x4){0.f, 0.f, 0.f, 0.f};
      zz = __builtin_amdgcn_mfma_f32_16x16x32_bf16(aq0, bk0, zz, 0, 0, 0);
      zz = __builtin_amdgcn_mfma_f32_16x16x32_bf16(aq1, bk1, zz, 0, 0, 0);
      sc[nt] = zz;
    }

    // ---- exp2 + causal mask + P store + partial sums
    const bool diag = (kt == qt);
#pragma unroll
    for (int nt = 0; nt < 4; ++nt) {
      int kg = kt * 64 + nt * 16 + l15;
#pragma unroll
      for (int r = 0; r < 4; ++r) {
        float p = __builtin_amdgcn_exp2f(sc[nt][r]);
        if (diag && kg > qrow0 + r) p = 0.f;
        Ps[w][quad * 4 + r][nt * 16 + l15] = f2b(p);
        rsl[r] += p;
      }
    }
    // Ps per-wave private: no barrier (lgkmcnt dependency handled)

    // ---- O += P . V
    bf16x8 ap0 = *(const bf16x8*)&Ps[w][l15][quad * 8];
    bf16x8 ap1 = *(const bf16x8*)&Ps[w][l15][32 + quad * 8];
#pragma unroll
    for (int nt = 0; nt < 4; ++nt) {
      const ushort* vr = &Vs[cur][(nt * 16 + l15) * 64];
      bf16x8 bv0 = *(const bf16x8*)(vr + sA);
      bf16x8 bv1 = *(const bf16x8*)(vr + sB);
      accO[nt] = __builtin_amdgcn_mfma_f32_16x16x32_bf16(ap0, bv0, accO[nt], 0, 0, 0);
      accO[nt] = __builtin_amdgcn_mfma_f32_16x16x32_bf16(ap1, bv1, accO[nt], 0, 0, 0);
    }
  }

  // ---- one-time row-sum reduction across 16 l15 lanes
#pragma unroll
  for (int r = 0; r < 4; ++r) {
#pragma unroll
    for (int off = 1; off < 16; off <<= 1) rsl[r] += __shfl_xor(rsl[r], off);
  }

  // ---- epilogue: attn_out bf16, (B,S,H*Dh)
#pragma unroll
  for (int r = 0; r < 4; ++r) {
    float invl = 1.f / rsl[r];
    int qrow = qt * 64 + w * 16 + quad * 4 + r;
    size_t base = ((size_t)(b * SEQ + qrow)) * D_MODEL + h * 64;
#pragma unroll
    for (int nt = 0; nt < 4; ++nt)
      O[base + nt * 16 + l15] = f2b(accO[nt][r] * invl);
  }
}

// ---------------------------------------------------------------------------
extern "C" void kernel_launch(void* const* d_in, const int* in_sizes, int n_in,
                              void* d_out, int out_size, void* d_ws, size_t ws_size,
                              hipStream_t stream) {
  const float* X  = (const float*)d_in[0];
  const float* Wq = (const float*)d_in[1];
  const float* Wk = (const float*)d_in[2];
  const float* Wv = (const float*)d_in[3];
  const float* Wo = (const float*)d_in[4];
  float* out = (float*)d_out;

  ushort* Xb  = (ushort*)d_ws;
  ushort* Wqb = Xb  + (size_t)MTOT * D_MODEL;
  ushort* Wkb = Wqb + (size_t)D_MODEL * D_MODEL;
  ushort* Wvb = Wkb + (size_t)D_MODEL * D_MODEL;
  ushort* Wob = Wvb + (size_t)D_MODEL * D_MODEL;
  ushort* Qw  = Wob + (size_t)D_MODEL * D_MODEL;
  ushort* Kw  = Qw  + (size_t)MTOT * D_MODEL;
  ushort* Vtw = Kw  + (size_t)MTOT * D_MODEL;  // (B,H,Dh,S)
  ushort* At  = Vtw + (size_t)MTOT * D_MODEL;
  float2* tbl = (float2*)(At + (size_t)MTOT * D_MODEL);  // 512 KB

  prep<<<8448, 256, 0, stream>>>(X, Wq, Wk, Wv, Wo, Xb, Wqb, Wkb, Wvb, Wob, tbl);

  // QKV projection; RoPE fused (table) on Q/K, Q pre-scaled; V transposed
  gemm_bf16<<<dim3(D_MODEL / 128, MTOT / 128, 3), 256, 0, stream>>>(
      Xb, Wqb, Wkb, Wvb, tbl, nullptr, Qw, Kw, Vtw, 1);

  flash_mfma<<<dim3(SEQ / 64, NHEAD, BATCH), 256, 0, stream>>>(Qw, Kw, Vtw, At);

  gemm_bf16<<<dim3(D_MODEL / 128, MTOT / 128, 1), 256, 0, stream>>>(
      At, Wob, nullptr, nullptr, tbl, out, nullptr, nullptr, nullptr, 0);
}

// Round 8
// 185.761 us; speedup vs baseline: 1.0966x; 1.0966x over previous
//
#include <hip/hip_runtime.h>
#include <hip/hip_bf16.h>
#include <math.h>

#define D_MODEL 1024
#define NHEAD 16
#define DHEAD 64
#define SEQ 2048
#define BATCH 2
#define MTOT (BATCH * SEQ)  // 4096

typedef __attribute__((ext_vector_type(8))) short bf16x8;   // 4 VGPRs = MFMA A/B frag
typedef __attribute__((ext_vector_type(4))) float f32x4;    // MFMA C/D frag

static __device__ __forceinline__ ushort f2b(float x) {
  __hip_bfloat16 h = __float2bfloat16(x);
  union { __hip_bfloat16 h; ushort u; } cv; cv.h = h; return cv.u;
}

// async global->LDS, 16B per lane (m97). LDS dest = wave-uniform base + lane*16.
#define GLLDS16(gp, lp)                                                     \
  __builtin_amdgcn_global_load_lds(                                         \
      (const __attribute__((address_space(1))) unsigned int*)(gp),          \
      (__attribute__((address_space(3))) unsigned int*)(lp), 16, 0, 0)

// 0.125 (1/sqrt(Dh)) * log2(e): folded into Q at projection; flash exp2's raw scores
#define QSCALE 0.18033688011112042f

// ---------------------------------------------------------------------------
// prep: fp32->bf16 for X + 4 weights, plus RoPE cos/sin table (2048 x 32
// float2, 512 KB -> L2-resident for the gemm epilogue).
// blocks [0,4096): X ; [4096,8192): weights ; [8192,8448): table.
// ---------------------------------------------------------------------------
__global__ __launch_bounds__(256)
void prep(const float* __restrict__ X, const float* __restrict__ Wq,
          const float* __restrict__ Wk, const float* __restrict__ Wv,
          const float* __restrict__ Wo, ushort* __restrict__ Xb,
          ushort* __restrict__ Wqb, ushort* __restrict__ Wkb,
          ushort* __restrict__ Wvb, ushort* __restrict__ Wob,
          float2* __restrict__ tbl) {
  int bid = blockIdx.x;
  if (bid >= 8192) {  // rope table: idx = s*32 + i
    int idx = (bid - 8192) * 256 + threadIdx.x;
    int s = idx >> 5, i = idx & 31;
    float inv = exp2f((float)i * -0.4152410118609203f);  // 10000^(-i/32)
    float sn, cs;
    sincosf((float)s * inv, &sn, &cs);
    tbl[idx] = make_float2(cs, sn);
    return;
  }
  const float* in;
  ushort* out;
  int i;
  if (bid < 4096) {
    in = X; out = Xb; i = bid * 256 + threadIdx.x;
  } else {
    int ws = (bid - 4096) >> 10;
    in = (ws == 0) ? Wq : (ws == 1) ? Wk : (ws == 2) ? Wv : Wo;
    out = (ws == 0) ? Wqb : (ws == 1) ? Wkb : (ws == 2) ? Wvb : Wob;
    i = ((bid - 4096) & 1023) * 256 + threadIdx.x;
  }
  float4 v = ((const float4*)in)[i];
  ushort4 o;
  o.x = f2b(v.x); o.y = f2b(v.y); o.z = f2b(v.z); o.w = f2b(v.w);
  ((ushort4*)out)[i] = o;
}

// ---------------------------------------------------------------------------
// bf16 MFMA GEMM (m97 staging, measured-best R6 config): out = A @ W^T.
// 128x128 tile, BK=32, 4 waves (2x2). global_load_lds(16B), chunk swizzle
// f(row)=((row>>2)^row)&3; reader slot quad^f(row) -> conflict-free
// ds_read_b128 (verified R6: SQ_LDS_BANK_CONFLICT=0).
// mode 1 (QKV, z = 0/1/2 = Q/K/V): RoPE-by-table on Q/K (+QSCALE on Q),
// V written directly transposed (B,H,Dh,S). mode 0: fp32 row-major out.
// ---------------------------------------------------------------------------
__global__ __launch_bounds__(256)
void gemm_bf16(const ushort* __restrict__ A,
               const ushort* __restrict__ W0, const ushort* __restrict__ W1,
               const ushort* __restrict__ W2,
               const float2* __restrict__ tbl,
               float* __restrict__ outF,
               ushort* __restrict__ o0, ushort* __restrict__ o1,
               ushort* __restrict__ o2, int mode) {
  __shared__ ushort As[128 * 32];
  __shared__ ushort Bs[128 * 32];
  const int tid = threadIdx.x;
  const int lane = tid & 63;
  const int w = tid >> 6;
  const int quad = lane >> 4, l15 = lane & 15;
  const int wy = w >> 1, wx = w & 1;
  const int m0 = blockIdx.y * 128, n0 = blockIdx.x * 128;
  const int z = blockIdx.z;
  const ushort* W = (z == 0) ? W0 : (z == 1) ? W1 : W2;
  ushort* outB = (z == 0) ? o0 : (z == 1) ? o1 : o2;

  // staging: thread t owns slots t and t+256 (rows r0, r0+64; same chunk)
  const int r0 = tid >> 2, c0 = tid & 3;
  const int gc = c0 ^ (((r0 >> 2) ^ r0) & 3);  // f(r0) == f(r0+64)
  const ushort* Ag0 = A + (size_t)(m0 + r0) * D_MODEL + gc * 8;
  const ushort* Ag1 = A + (size_t)(m0 + r0 + 64) * D_MODEL + gc * 8;
  const ushort* Wg0 = W + (size_t)(n0 + r0) * D_MODEL + gc * 8;
  const ushort* Wg1 = W + (size_t)(n0 + r0 + 64) * D_MODEL + gc * 8;

  // reader chunk slot: f(row) = ((l15>>2) ^ l15) & 3 (mt/wy parts ≡ 0 mod 4)
  const int sw = (quad ^ (l15 >> 2) ^ l15) & 3;

  f32x4 acc[4][4];
#pragma unroll
  for (int i = 0; i < 4; ++i)
#pragma unroll
    for (int j = 0; j < 4; ++j) acc[i][j] = (f32x4){0.f, 0.f, 0.f, 0.f};

  for (int kt = 0; kt < D_MODEL / 32; ++kt) {
    if (kt) __syncthreads();
    GLLDS16(Ag0 + kt * 32, &As[(size_t)tid * 8]);
    GLLDS16(Ag1 + kt * 32, &As[(size_t)(tid + 256) * 8]);
    GLLDS16(Wg0 + kt * 32, &Bs[(size_t)tid * 8]);
    GLLDS16(Wg1 + kt * 32, &Bs[(size_t)(tid + 256) * 8]);
    __syncthreads();  // compiler drains vmcnt before barrier

    bf16x8 af[4], bfr[4];
#pragma unroll
    for (int mt = 0; mt < 4; ++mt) {
      int row = wy * 64 + mt * 16 + l15;
      af[mt] = *(const bf16x8*)&As[(row * 4 + sw) * 8];
    }
#pragma unroll
    for (int nt = 0; nt < 4; ++nt) {
      int row = wx * 64 + nt * 16 + l15;
      bfr[nt] = *(const bf16x8*)&Bs[(row * 4 + sw) * 8];
    }
#pragma unroll
    for (int mt = 0; mt < 4; ++mt)
#pragma unroll
      for (int nt = 0; nt < 4; ++nt)
        acc[mt][nt] = __builtin_amdgcn_mfma_f32_16x16x32_bf16(
            af[mt], bfr[nt], acc[mt][nt], 0, 0, 0);
  }

  // ---- epilogue. C/D: row = quad*4+r, col = l15 per 16x16 tile.
  const float qsc = (z == 0) ? QSCALE : 1.0f;
#pragma unroll
  for (int mt = 0; mt < 4; ++mt) {
    int m_base = m0 + wy * 64 + mt * 16 + quad * 4;
    int b = m_base >> 11, s_base = m_base & (SEQ - 1);
#pragma unroll
    for (int nt = 0; nt < 4; ++nt) {
      int n = n0 + wx * 64 + nt * 16 + l15;
      if (mode == 0) {
#pragma unroll
        for (int r = 0; r < 4; ++r)
          outF[(size_t)(m_base + r) * D_MODEL + n] = acc[mt][nt][r];
      } else {
        int h = n >> 6, dh = n & 63;
        if (z == 2) {  // V: transposed store, 4 consecutive s in one ushort4
          ushort4 o;
          o.x = f2b(acc[mt][nt][0]); o.y = f2b(acc[mt][nt][1]);
          o.z = f2b(acc[mt][nt][2]); o.w = f2b(acc[mt][nt][3]);
          *(ushort4*)&outB[((size_t)(b * NHEAD + h) * DHEAD + dh) * SEQ + s_base] = o;
        } else {       // Q/K: RoPE via table, pair partner via lane shuffle
          int i = nt * 8 + (l15 >> 1);   // freq index, pair-uniform
          bool evn = !(l15 & 1);
#pragma unroll
          for (int r = 0; r < 4; ++r) {
            float v = acc[mt][nt][r];
            float pv = __shfl_xor(v, 1);
            float2 csn = tbl[(s_base + r) * 32 + i];
            v = v * csn.x + (evn ? -pv * csn.y : pv * csn.y);
            v *= qsc;
            outB[(((size_t)(b * NHEAD + h)) * SEQ + s_base + r) * DHEAD + dh] = f2b(v);
          }
        }
      }
    }
  }
}

// ---------------------------------------------------------------------------
// bf16 MFMA causal flash attention, no-max-shift softmax (scores bounded;
// Q pre-scaled by QSCALE at projection so exp2 applies directly).
// Staging = REGISTER PREFETCH (measured-best, R3): K/V tile kt+1 loaded into
// 16 VGPRs during tile-kt compute, ds_write after the barrier -> full
// cross-tile global-latency overlap with NO extra LDS (27 KB, ~2x occupancy
// of the dbuf variant). K/V LDS padded [64][72]: frag reads + stores 2-way
// max (free). Ps stride 68: 2-way (free) -- R3's 4-way defect fixed.
// Per-lane partial row sums, one shuffle-reduce in epilogue. Heads 8-15
// walk qt reversed to balance ktiles across CUs.
// ---------------------------------------------------------------------------
__global__ __launch_bounds__(256)
void flash_mfma(const ushort* __restrict__ Q, const ushort* __restrict__ K,
                const ushort* __restrict__ Vt, ushort* __restrict__ O) {
  __shared__ ushort Ks[64][72];      // [key][dh]
  __shared__ ushort Vs[64][72];      // [dh][key]
  __shared__ ushort Ps[4][16][68];   // per-wave P: [qrow][key]
  const int tid = threadIdx.x;
  const int lane = tid & 63, w = tid >> 6;
  const int quad = lane >> 4, l15 = lane & 15;
  const int h = blockIdx.y, b = blockIdx.z;
  const int qt = (h >= 8) ? (31 - blockIdx.x) : blockIdx.x;
  const int bh = b * NHEAD + h;

  // Q fragments: plain global read, live whole loop (pre-scaled + roped)
  const ushort* Qrow = Q + ((size_t)bh * SEQ + qt * 64 + w * 16 + l15) * 64;
  bf16x8 aq0 = *(const bf16x8*)(Qrow + quad * 8);
  bf16x8 aq1 = *(const bf16x8*)(Qrow + 32 + quad * 8);

  // staging: thread owns rows sr and sr+32, 16B chunk sc8
  const int sr = tid >> 3, sc8 = (tid & 7) * 8;
  const ushort* Kg0 = K + ((size_t)bh * SEQ + sr) * 64 + sc8;
  const ushort* Kg1 = Kg0 + (size_t)32 * 64;
  const ushort* Vg0 = Vt + ((size_t)bh * 64 + sr) * SEQ + sc8;
  const ushort* Vg1 = Vg0 + (size_t)32 * SEQ;

  float rsl[4];
  f32x4 accO[4];
#pragma unroll
  for (int r = 0; r < 4; ++r) rsl[r] = 0.f;
#pragma unroll
  for (int nt = 0; nt < 4; ++nt) accO[nt] = (f32x4){0.f, 0.f, 0.f, 0.f};

  float4 pk0 = *(const float4*)(Kg0);
  float4 pk1 = *(const float4*)(Kg1);
  float4 pv0 = *(const float4*)(Vg0);
  float4 pv1 = *(const float4*)(Vg1);

  const int qrow0 = qt * 64 + w * 16 + quad * 4;

  for (int kt = 0; kt <= qt; ++kt) {
    __syncthreads();  // prior iter's LDS reads complete
    *(float4*)&Ks[sr][sc8]      = pk0;
    *(float4*)&Ks[sr + 32][sc8] = pk1;
    *(float4*)&Vs[sr][sc8]      = pv0;
    *(float4*)&Vs[sr + 32][sc8] = pv1;
    __syncthreads();
    if (kt < qt) {  // prefetch kt+1 into registers; overlaps all compute below
      pk0 = *(const float4*)(Kg0 + (size_t)(kt + 1) * 64 * 64);
      pk1 = *(const float4*)(Kg1 + (size_t)(kt + 1) * 64 * 64);
      pv0 = *(const float4*)(Vg0 + (kt + 1) * 64);
      pv1 = *(const float4*)(Vg1 + (kt + 1) * 64);
    }

    // ---- scores = Q . K^T (exp2 units)
    f32x4 sc[4];
#pragma unroll
    for (int nt = 0; nt < 4; ++nt) {
      const ushort* kr = &Ks[nt * 16 + l15][0];
      bf16x8 bk0 = *(const bf16x8*)(kr + quad * 8);
      bf16x8 bk1 = *(const bf16x8*)(kr + 32 + quad * 8);
      f32x4 zz = (f32x4){0.f, 0.f, 0.f, 0.f};
      zz = __builtin_amdgcn_mfma_f32_16x16x32_bf16(aq0, bk0, zz, 0, 0, 0);
      zz = __builtin_amdgcn_mfma_f32_16x16x32_bf16(aq1, bk1, zz, 0, 0, 0);
      sc[nt] = zz;
    }

    // ---- exp2 + causal mask + P store + partial sums
    const bool diag = (kt == qt);
#pragma unroll
    for (int nt = 0; nt < 4; ++nt) {
      int kg = kt * 64 + nt * 16 + l15;
#pragma unroll
      for (int r = 0; r < 4; ++r) {
        float p = __builtin_amdgcn_exp2f(sc[nt][r]);
        if (diag && kg > qrow0 + r) p = 0.f;
        Ps[w][quad * 4 + r][nt * 16 + l15] = f2b(p);
        rsl[r] += p;
      }
    }
    // Ps per-wave private: no barrier (lgkmcnt dependency handled)

    // ---- O += P . V
    bf16x8 ap0 = *(const bf16x8*)&Ps[w][l15][quad * 8];
    bf16x8 ap1 = *(const bf16x8*)&Ps[w][l15][32 + quad * 8];
#pragma unroll
    for (int nt = 0; nt < 4; ++nt) {
      const ushort* vr = &Vs[nt * 16 + l15][0];
      bf16x8 bv0 = *(const bf16x8*)(vr + quad * 8);
      bf16x8 bv1 = *(const bf16x8*)(vr + 32 + quad * 8);
      accO[nt] = __builtin_amdgcn_mfma_f32_16x16x32_bf16(ap0, bv0, accO[nt], 0, 0, 0);
      accO[nt] = __builtin_amdgcn_mfma_f32_16x16x32_bf16(ap1, bv1, accO[nt], 0, 0, 0);
    }
  }

  // ---- one-time row-sum reduction across 16 l15 lanes
#pragma unroll
  for (int r = 0; r < 4; ++r) {
#pragma unroll
    for (int off = 1; off < 16; off <<= 1) rsl[r] += __shfl_xor(rsl[r], off);
  }

  // ---- epilogue: attn_out bf16, (B,S,H*Dh)
#pragma unroll
  for (int r = 0; r < 4; ++r) {
    float invl = 1.f / rsl[r];
    int qrow = qt * 64 + w * 16 + quad * 4 + r;
    size_t base = ((size_t)(b * SEQ + qrow)) * D_MODEL + h * 64;
#pragma unroll
    for (int nt = 0; nt < 4; ++nt)
      O[base + nt * 16 + l15] = f2b(accO[nt][r] * invl);
  }
}

// ---------------------------------------------------------------------------
extern "C" void kernel_launch(void* const* d_in, const int* in_sizes, int n_in,
                              void* d_out, int out_size, void* d_ws, size_t ws_size,
                              hipStream_t stream) {
  const float* X  = (const float*)d_in[0];
  const float* Wq = (const float*)d_in[1];
  const float* Wk = (const float*)d_in[2];
  const float* Wv = (const float*)d_in[3];
  const float* Wo = (const float*)d_in[4];
  float* out = (float*)d_out;

  ushort* Xb  = (ushort*)d_ws;
  ushort* Wqb = Xb  + (size_t)MTOT * D_MODEL;
  ushort* Wkb = Wqb + (size_t)D_MODEL * D_MODEL;
  ushort* Wvb = Wkb + (size_t)D_MODEL * D_MODEL;
  ushort* Wob = Wvb + (size_t)D_MODEL * D_MODEL;
  ushort* Qw  = Wob + (size_t)D_MODEL * D_MODEL;
  ushort* Kw  = Qw  + (size_t)MTOT * D_MODEL;
  ushort* Vtw = Kw  + (size_t)MTOT * D_MODEL;  // (B,H,Dh,S)
  ushort* At  = Vtw + (size_t)MTOT * D_MODEL;
  float2* tbl = (float2*)(At + (size_t)MTOT * D_MODEL);  // 512 KB

  prep<<<8448, 256, 0, stream>>>(X, Wq, Wk, Wv, Wo, Xb, Wqb, Wkb, Wvb, Wob, tbl);

  // QKV projection; RoPE fused (table) on Q/K, Q pre-scaled; V transposed
  gemm_bf16<<<dim3(D_MODEL / 128, MTOT / 128, 3), 256, 0, stream>>>(
      Xb, Wqb, Wkb, Wvb, tbl, nullptr, Qw, Kw, Vtw, 1);

  flash_mfma<<<dim3(SEQ / 64, NHEAD, BATCH), 256, 0, stream>>>(Qw, Kw, Vtw, At);

  gemm_bf16<<<dim3(D_MODEL / 128, MTOT / 128, 1), 256, 0, stream>>>(
      At, Wob, nullptr, nullptr, tbl, out, nullptr, nullptr, nullptr, 0);
}

// Round 9
// 180.036 us; speedup vs baseline: 1.1315x; 1.0318x over previous
//
#include <hip/hip_runtime.h>
#include <hip/hip_bf16.h>
#include <math.h>

#define D_MODEL 1024
#define NHEAD 16
#define DHEAD 64
#define SEQ 2048
#define BATCH 2
#define MTOT (BATCH * SEQ)  // 4096

typedef __attribute__((ext_vector_type(8))) short bf16x8;   // 4 VGPRs = MFMA A/B frag
typedef __attribute__((ext_vector_type(4))) float f32x4;    // MFMA C/D frag

static __device__ __forceinline__ ushort f2b(float x) {
  __hip_bfloat16 h = __float2bfloat16(x);
  union { __hip_bfloat16 h; ushort u; } cv; cv.h = h; return cv.u;
}

// async global->LDS, 16B per lane (m97). LDS dest = wave-uniform base + lane*16.
#define GLLDS16(gp, lp)                                                     \
  __builtin_amdgcn_global_load_lds(                                         \
      (const __attribute__((address_space(1))) unsigned int*)(gp),          \
      (__attribute__((address_space(3))) unsigned int*)(lp), 16, 0, 0)

// 0.125 (1/sqrt(Dh)) * log2(e): folded into Q at projection; flash exp2's raw scores
#define QSCALE 0.18033688011112042f

// ---------------------------------------------------------------------------
// prep: fp32->bf16 for X + 4 weights, plus RoPE cos/sin table (2048 x 32
// float2, 512 KB -> L2-resident for the gemm epilogue).
// blocks [0,4096): X ; [4096,8192): weights ; [8192,8448): table.
// ---------------------------------------------------------------------------
__global__ __launch_bounds__(256)
void prep(const float* __restrict__ X, const float* __restrict__ Wq,
          const float* __restrict__ Wk, const float* __restrict__ Wv,
          const float* __restrict__ Wo, ushort* __restrict__ Xb,
          ushort* __restrict__ Wqb, ushort* __restrict__ Wkb,
          ushort* __restrict__ Wvb, ushort* __restrict__ Wob,
          float2* __restrict__ tbl) {
  int bid = blockIdx.x;
  if (bid >= 8192) {  // rope table: idx = s*32 + i
    int idx = (bid - 8192) * 256 + threadIdx.x;
    int s = idx >> 5, i = idx & 31;
    float inv = exp2f((float)i * -0.4152410118609203f);  // 10000^(-i/32)
    float sn, cs;
    sincosf((float)s * inv, &sn, &cs);
    tbl[idx] = make_float2(cs, sn);
    return;
  }
  const float* in;
  ushort* out;
  int i;
  if (bid < 4096) {
    in = X; out = Xb; i = bid * 256 + threadIdx.x;
  } else {
    int ws = (bid - 4096) >> 10;
    in = (ws == 0) ? Wq : (ws == 1) ? Wk : (ws == 2) ? Wv : Wo;
    out = (ws == 0) ? Wqb : (ws == 1) ? Wkb : (ws == 2) ? Wvb : Wob;
    i = ((bid - 4096) & 1023) * 256 + threadIdx.x;
  }
  float4 v = ((const float4*)in)[i];
  ushort4 o;
  o.x = f2b(v.x); o.y = f2b(v.y); o.z = f2b(v.z); o.w = f2b(v.w);
  ((ushort4*)out)[i] = o;
}

// ---------------------------------------------------------------------------
// bf16 MFMA GEMM (m97 staging, measured-best R6 config): out = A @ W^T.
// 128x128 tile, BK=32, 4 waves (2x2). global_load_lds(16B), chunk swizzle
// f(row)=((row>>2)^row)&3; reader slot quad^f(row) -> conflict-free
// ds_read_b128 (verified R6: SQ_LDS_BANK_CONFLICT=0).
// mode 1 (QKV, z = 0/1/2 = Q/K/V): RoPE-by-table on Q/K (+QSCALE on Q),
// V written directly transposed (B,H,Dh,S). mode 0: fp32 row-major out.
// ---------------------------------------------------------------------------
__global__ __launch_bounds__(256)
void gemm_bf16(const ushort* __restrict__ A,
               const ushort* __restrict__ W0, const ushort* __restrict__ W1,
               const ushort* __restrict__ W2,
               const float2* __restrict__ tbl,
               float* __restrict__ outF,
               ushort* __restrict__ o0, ushort* __restrict__ o1,
               ushort* __restrict__ o2, int mode) {
  __shared__ ushort As[128 * 32];
  __shared__ ushort Bs[128 * 32];
  const int tid = threadIdx.x;
  const int lane = tid & 63;
  const int w = tid >> 6;
  const int quad = lane >> 4, l15 = lane & 15;
  const int wy = w >> 1, wx = w & 1;
  const int m0 = blockIdx.y * 128, n0 = blockIdx.x * 128;
  const int z = blockIdx.z;
  const ushort* W = (z == 0) ? W0 : (z == 1) ? W1 : W2;
  ushort* outB = (z == 0) ? o0 : (z == 1) ? o1 : o2;

  // staging: thread t owns slots t and t+256 (rows r0, r0+64; same chunk)
  const int r0 = tid >> 2, c0 = tid & 3;
  const int gc = c0 ^ (((r0 >> 2) ^ r0) & 3);  // f(r0) == f(r0+64)
  const ushort* Ag0 = A + (size_t)(m0 + r0) * D_MODEL + gc * 8;
  const ushort* Ag1 = A + (size_t)(m0 + r0 + 64) * D_MODEL + gc * 8;
  const ushort* Wg0 = W + (size_t)(n0 + r0) * D_MODEL + gc * 8;
  const ushort* Wg1 = W + (size_t)(n0 + r0 + 64) * D_MODEL + gc * 8;

  // reader chunk slot: f(row) = ((l15>>2) ^ l15) & 3 (mt/wy parts ≡ 0 mod 4)
  const int sw = (quad ^ (l15 >> 2) ^ l15) & 3;

  f32x4 acc[4][4];
#pragma unroll
  for (int i = 0; i < 4; ++i)
#pragma unroll
    for (int j = 0; j < 4; ++j) acc[i][j] = (f32x4){0.f, 0.f, 0.f, 0.f};

  for (int kt = 0; kt < D_MODEL / 32; ++kt) {
    if (kt) __syncthreads();
    GLLDS16(Ag0 + kt * 32, &As[(size_t)tid * 8]);
    GLLDS16(Ag1 + kt * 32, &As[(size_t)(tid + 256) * 8]);
    GLLDS16(Wg0 + kt * 32, &Bs[(size_t)tid * 8]);
    GLLDS16(Wg1 + kt * 32, &Bs[(size_t)(tid + 256) * 8]);
    __syncthreads();  // compiler drains vmcnt before barrier

    bf16x8 af[4], bfr[4];
#pragma unroll
    for (int mt = 0; mt < 4; ++mt) {
      int row = wy * 64 + mt * 16 + l15;
      af[mt] = *(const bf16x8*)&As[(row * 4 + sw) * 8];
    }
#pragma unroll
    for (int nt = 0; nt < 4; ++nt) {
      int row = wx * 64 + nt * 16 + l15;
      bfr[nt] = *(const bf16x8*)&Bs[(row * 4 + sw) * 8];
    }
#pragma unroll
    for (int mt = 0; mt < 4; ++mt)
#pragma unroll
      for (int nt = 0; nt < 4; ++nt)
        acc[mt][nt] = __builtin_amdgcn_mfma_f32_16x16x32_bf16(
            af[mt], bfr[nt], acc[mt][nt], 0, 0, 0);
  }

  // ---- epilogue. C/D: row = quad*4+r, col = l15 per 16x16 tile.
  const float qsc = (z == 0) ? QSCALE : 1.0f;
#pragma unroll
  for (int mt = 0; mt < 4; ++mt) {
    int m_base = m0 + wy * 64 + mt * 16 + quad * 4;
    int b = m_base >> 11, s_base = m_base & (SEQ - 1);
#pragma unroll
    for (int nt = 0; nt < 4; ++nt) {
      int n = n0 + wx * 64 + nt * 16 + l15;
      if (mode == 0) {
#pragma unroll
        for (int r = 0; r < 4; ++r)
          outF[(size_t)(m_base + r) * D_MODEL + n] = acc[mt][nt][r];
      } else {
        int h = n >> 6, dh = n & 63;
        if (z == 2) {  // V: transposed store, 4 consecutive s in one ushort4
          ushort4 o;
          o.x = f2b(acc[mt][nt][0]); o.y = f2b(acc[mt][nt][1]);
          o.z = f2b(acc[mt][nt][2]); o.w = f2b(acc[mt][nt][3]);
          *(ushort4*)&outB[((size_t)(b * NHEAD + h) * DHEAD + dh) * SEQ + s_base] = o;
        } else {       // Q/K: RoPE via table, pair partner via lane shuffle
          int i = nt * 8 + (l15 >> 1);   // freq index, pair-uniform
          bool evn = !(l15 & 1);
#pragma unroll
          for (int r = 0; r < 4; ++r) {
            float v = acc[mt][nt][r];
            float pv = __shfl_xor(v, 1);
            float2 csn = tbl[(s_base + r) * 32 + i];
            v = v * csn.x + (evn ? -pv * csn.y : pv * csn.y);
            v *= qsc;
            outB[(((size_t)(b * NHEAD + h)) * SEQ + s_base + r) * DHEAD + dh] = f2b(v);
          }
        }
      }
    }
  }
}

// ---------------------------------------------------------------------------
// bf16 MFMA causal flash attention, no-max-shift softmax (scores bounded;
// Q pre-scaled by QSCALE at projection so exp2 applies directly).
// Staging = register prefetch (R8's win: K/V tile kt+1 loaded into VGPRs
// during tile-kt compute, full cross-tile latency overlap, no extra LDS)
// INTO R6's measured-conflict-free LDS geometry: UNPADDED [64][64] tiles,
// slot c of row r holds global chunk c^(r&7); thread ds_write dests are
// tid*8 / 2048+tid*8 (identical addresses to R6's DMA writes); fragment
// readers at chunk quad^(l15&7) (R6: SQ_LDS_BANK_CONFLICT=0).
// Ps stride 68: clean per R6. Per-lane partial row sums, one shuffle-reduce
// in epilogue. Heads 8-15 walk qt reversed to balance ktiles across CUs.
// ---------------------------------------------------------------------------
__global__ __launch_bounds__(256)
void flash_mfma(const ushort* __restrict__ Q, const ushort* __restrict__ K,
                const ushort* __restrict__ Vt, ushort* __restrict__ O) {
  __shared__ ushort Ks[64 * 64];     // [key][dh], chunk-swizzled
  __shared__ ushort Vs[64 * 64];     // [dh][key], chunk-swizzled
  __shared__ ushort Ps[4][16][68];   // per-wave P: [qrow][key]
  const int tid = threadIdx.x;
  const int lane = tid & 63, w = tid >> 6;
  const int quad = lane >> 4, l15 = lane & 15;
  const int h = blockIdx.y, b = blockIdx.z;
  const int qt = (h >= 8) ? (31 - blockIdx.x) : blockIdx.x;
  const int bh = b * NHEAD + h;

  // Q fragments: plain global read, live whole loop (pre-scaled + roped)
  const ushort* Qrow = Q + ((size_t)bh * SEQ + qt * 64 + w * 16 + l15) * 64;
  bf16x8 aq0 = *(const bf16x8*)(Qrow + quad * 8);
  bf16x8 aq1 = *(const bf16x8*)(Qrow + 32 + quad * 8);

  // staging: thread owns rows rl and rl+32, LDS slot tid&7, global chunk XOR'd
  const int rl = tid >> 3;
  const int gsc = (tid & 7) ^ (rl & 7);  // (rl+32)&7 == rl&7
  const ushort* Kg0 = K + ((size_t)bh * SEQ + rl) * 64 + gsc * 8;
  const ushort* Kg1 = Kg0 + (size_t)32 * 64;
  const ushort* Vg0 = Vt + ((size_t)bh * 64 + rl) * SEQ + gsc * 8;
  const ushort* Vg1 = Vg0 + (size_t)32 * SEQ;

  // reader chunk slots: slot quad^(r&7) holds chunk quad; frag rows have r&7==l15&7
  const int sA = (quad ^ (l15 & 7)) * 8;  // k/keys 0..31
  const int sB = sA ^ 32;                 // k/keys 32..63 (chunk quad+4)

  float rsl[4];
  f32x4 accO[4];
#pragma unroll
  for (int r = 0; r < 4; ++r) rsl[r] = 0.f;
#pragma unroll
  for (int nt = 0; nt < 4; ++nt) accO[nt] = (f32x4){0.f, 0.f, 0.f, 0.f};

  float4 pk0 = *(const float4*)(Kg0);
  float4 pk1 = *(const float4*)(Kg1);
  float4 pv0 = *(const float4*)(Vg0);
  float4 pv1 = *(const float4*)(Vg1);

  const int qrow0 = qt * 64 + w * 16 + quad * 4;

  for (int kt = 0; kt <= qt; ++kt) {
    __syncthreads();  // prior iter's LDS reads complete
    *(float4*)&Ks[tid * 8]        = pk0;   // row rl,    slot tid&7
    *(float4*)&Ks[2048 + tid * 8] = pk1;   // row rl+32, slot tid&7
    *(float4*)&Vs[tid * 8]        = pv0;
    *(float4*)&Vs[2048 + tid * 8] = pv1;
    __syncthreads();
    if (kt < qt) {  // prefetch kt+1 into registers; overlaps all compute below
      pk0 = *(const float4*)(Kg0 + (size_t)(kt + 1) * 64 * 64);
      pk1 = *(const float4*)(Kg1 + (size_t)(kt + 1) * 64 * 64);
      pv0 = *(const float4*)(Vg0 + (kt + 1) * 64);
      pv1 = *(const float4*)(Vg1 + (kt + 1) * 64);
    }

    // ---- scores = Q . K^T (exp2 units)
    f32x4 sc[4];
#pragma unroll
    for (int nt = 0; nt < 4; ++nt) {
      const ushort* kr = &Ks[(nt * 16 + l15) * 64];
      bf16x8 bk0 = *(const bf16x8*)(kr + sA);
      bf16x8 bk1 = *(const bf16x8*)(kr + sB);
      f32x4 zz = (f32x4){0.f, 0.f, 0.f, 0.f};
      zz = __builtin_amdgcn_mfma_f32_16x16x32_bf16(aq0, bk0, zz, 0, 0, 0);
      zz = __builtin_amdgcn_mfma_f32_16x16x32_bf16(aq1, bk1, zz, 0, 0, 0);
      sc[nt] = zz;
    }

    // ---- exp2 + causal mask + P store + partial sums
    const bool diag = (kt == qt);
#pragma unroll
    for (int nt = 0; nt < 4; ++nt) {
      int kg = kt * 64 + nt * 16 + l15;
#pragma unroll
      for (int r = 0; r < 4; ++r) {
        float p = __builtin_amdgcn_exp2f(sc[nt][r]);
        if (diag && kg > qrow0 + r) p = 0.f;
        Ps[w][quad * 4 + r][nt * 16 + l15] = f2b(p);
        rsl[r] += p;
      }
    }
    // Ps per-wave private: no barrier (lgkmcnt dependency handled)

    // ---- O += P . V
    bf16x8 ap0 = *(const bf16x8*)&Ps[w][l15][quad * 8];
    bf16x8 ap1 = *(const bf16x8*)&Ps[w][l15][32 + quad * 8];
#pragma unroll
    for (int nt = 0; nt < 4; ++nt) {
      const ushort* vr = &Vs[(nt * 16 + l15) * 64];
      bf16x8 bv0 = *(const bf16x8*)(vr + sA);
      bf16x8 bv1 = *(const bf16x8*)(vr + sB);
      accO[nt] = __builtin_amdgcn_mfma_f32_16x16x32_bf16(ap0, bv0, accO[nt], 0, 0, 0);
      accO[nt] = __builtin_amdgcn_mfma_f32_16x16x32_bf16(ap1, bv1, accO[nt], 0, 0, 0);
    }
  }

  // ---- one-time row-sum reduction across 16 l15 lanes
#pragma unroll
  for (int r = 0; r < 4; ++r) {
#pragma unroll
    for (int off = 1; off < 16; off <<= 1) rsl[r] += __shfl_xor(rsl[r], off);
  }

  // ---- epilogue: attn_out bf16, (B,S,H*Dh)
#pragma unroll
  for (int r = 0; r < 4; ++r) {
    float invl = 1.f / rsl[r];
    int qrow = qt * 64 + w * 16 + quad * 4 + r;
    size_t base = ((size_t)(b * SEQ + qrow)) * D_MODEL + h * 64;
#pragma unroll
    for (int nt = 0; nt < 4; ++nt)
      O[base + nt * 16 + l15] = f2b(accO[nt][r] * invl);
  }
}

// ---------------------------------------------------------------------------
extern "C" void kernel_launch(void* const* d_in, const int* in_sizes, int n_in,
                              void* d_out, int out_size, void* d_ws, size_t ws_size,
                              hipStream_t stream) {
  const float* X  = (const float*)d_in[0];
  const float* Wq = (const float*)d_in[1];
  const float* Wk = (const float*)d_in[2];
  const float* Wv = (const float*)d_in[3];
  const float* Wo = (const float*)d_in[4];
  float* out = (float*)d_out;

  ushort* Xb  = (ushort*)d_ws;
  ushort* Wqb = Xb  + (size_t)MTOT * D_MODEL;
  ushort* Wkb = Wqb + (size_t)D_MODEL * D_MODEL;
  ushort* Wvb = Wkb + (size_t)D_MODEL * D_MODEL;
  ushort* Wob = Wvb + (size_t)D_MODEL * D_MODEL;
  ushort* Qw  = Wob + (size_t)D_MODEL * D_MODEL;
  ushort* Kw  = Qw  + (size_t)MTOT * D_MODEL;
  ushort* Vtw = Kw  + (size_t)MTOT * D_MODEL;  // (B,H,Dh,S)
  ushort* At  = Vtw + (size_t)MTOT * D_MODEL;
  float2* tbl = (float2*)(At + (size_t)MTOT * D_MODEL);  // 512 KB

  prep<<<8448, 256, 0, stream>>>(X, Wq, Wk, Wv, Wo, Xb, Wqb, Wkb, Wvb, Wob, tbl);

  // QKV projection; RoPE fused (table) on Q/K, Q pre-scaled; V transposed
  gemm_bf16<<<dim3(D_MODEL / 128, MTOT / 128, 3), 256, 0, stream>>>(
      Xb, Wqb, Wkb, Wvb, tbl, nullptr, Qw, Kw, Vtw, 1);

  flash_mfma<<<dim3(SEQ / 64, NHEAD, BATCH), 256, 0, stream>>>(Qw, Kw, Vtw, At);

  gemm_bf16<<<dim3(D_MODEL / 128, MTOT / 128, 1), 256, 0, stream>>>(
      At, Wob, nullptr, nullptr, tbl, out, nullptr, nullptr, nullptr, 0);
}

// Round 10
// 175.521 us; speedup vs baseline: 1.1606x; 1.0257x over previous
//
#include <hip/hip_runtime.h>
#include <hip/hip_bf16.h>
#include <math.h>

#define D_MODEL 1024
#define NHEAD 16
#define DHEAD 64
#define SEQ 2048
#define BATCH 2
#define MTOT (BATCH * SEQ)  // 4096

typedef __attribute__((ext_vector_type(8))) short bf16x8;   // 4 VGPRs = MFMA A/B frag
typedef __attribute__((ext_vector_type(4))) float f32x4;    // MFMA C/D frag

static __device__ __forceinline__ ushort f2b(float x) {
  __hip_bfloat16 h = __float2bfloat16(x);
  union { __hip_bfloat16 h; ushort u; } cv; cv.h = h; return cv.u;
}

// async global->LDS, 16B per lane (m97). LDS dest = wave-uniform base + lane*16.
#define GLLDS16(gp, lp)                                                     \
  __builtin_amdgcn_global_load_lds(                                         \
      (const __attribute__((address_space(1))) unsigned int*)(gp),          \
      (__attribute__((address_space(3))) unsigned int*)(lp), 16, 0, 0)

// 0.125 (1/sqrt(Dh)) * log2(e): folded into Q at projection; flash exp2's raw scores
#define QSCALE 0.18033688011112042f

// ---------------------------------------------------------------------------
// prep: fp32->bf16 for X + 4 weights, plus RoPE cos/sin table.
// ---------------------------------------------------------------------------
__global__ __launch_bounds__(256)
void prep(const float* __restrict__ X, const float* __restrict__ Wq,
          const float* __restrict__ Wk, const float* __restrict__ Wv,
          const float* __restrict__ Wo, ushort* __restrict__ Xb,
          ushort* __restrict__ Wqb, ushort* __restrict__ Wkb,
          ushort* __restrict__ Wvb, ushort* __restrict__ Wob,
          float2* __restrict__ tbl) {
  int bid = blockIdx.x;
  if (bid >= 8192) {  // rope table: idx = s*32 + i
    int idx = (bid - 8192) * 256 + threadIdx.x;
    int s = idx >> 5, i = idx & 31;
    float inv = exp2f((float)i * -0.4152410118609203f);  // 10000^(-i/32)
    float sn, cs;
    sincosf((float)s * inv, &sn, &cs);
    tbl[idx] = make_float2(cs, sn);
    return;
  }
  const float* in;
  ushort* out;
  int i;
  if (bid < 4096) {
    in = X; out = Xb; i = bid * 256 + threadIdx.x;
  } else {
    int ws = (bid - 4096) >> 10;
    in = (ws == 0) ? Wq : (ws == 1) ? Wk : (ws == 2) ? Wv : Wo;
    out = (ws == 0) ? Wqb : (ws == 1) ? Wkb : (ws == 2) ? Wvb : Wob;
    i = ((bid - 4096) & 1023) * 256 + threadIdx.x;
  }
  float4 v = ((const float4*)in)[i];
  ushort4 o;
  o.x = f2b(v.x); o.y = f2b(v.y); o.z = f2b(v.z); o.w = f2b(v.w);
  ((ushort4*)out)[i] = o;
}

// ---------------------------------------------------------------------------
// bf16 MFMA GEMM (m97 staging, measured-best R6 config): out = A @ W^T.
// Conflict-free chunk swizzle (R6: SQ_LDS_BANK_CONFLICT=0).
// mode 1 (QKV): RoPE-by-table on Q/K (+QSCALE on Q); V written transposed
// (B,H,Dh,S) with KEY-PERMUTED columns pos(s) = 32*(s>>5) + ((s>>2)&3)*8 +
// ((s>>4)&1)*4 + (s&3) -- matches the MFMA k-slot order of flash's S^T
// C-regs, so flash feeds P^T into the PV MFMA straight from registers.
// mode 0: fp32 row-major store (final output).
// ---------------------------------------------------------------------------
__global__ __launch_bounds__(256)
void gemm_bf16(const ushort* __restrict__ A,
               const ushort* __restrict__ W0, const ushort* __restrict__ W1,
               const ushort* __restrict__ W2,
               const float2* __restrict__ tbl,
               float* __restrict__ outF,
               ushort* __restrict__ o0, ushort* __restrict__ o1,
               ushort* __restrict__ o2, int mode) {
  __shared__ ushort As[128 * 32];
  __shared__ ushort Bs[128 * 32];
  const int tid = threadIdx.x;
  const int lane = tid & 63;
  const int w = tid >> 6;
  const int quad = lane >> 4, l15 = lane & 15;
  const int wy = w >> 1, wx = w & 1;
  const int m0 = blockIdx.y * 128, n0 = blockIdx.x * 128;
  const int z = blockIdx.z;
  const ushort* W = (z == 0) ? W0 : (z == 1) ? W1 : W2;
  ushort* outB = (z == 0) ? o0 : (z == 1) ? o1 : o2;

  const int r0 = tid >> 2, c0 = tid & 3;
  const int gc = c0 ^ (((r0 >> 2) ^ r0) & 3);  // f(r0) == f(r0+64)
  const ushort* Ag0 = A + (size_t)(m0 + r0) * D_MODEL + gc * 8;
  const ushort* Ag1 = A + (size_t)(m0 + r0 + 64) * D_MODEL + gc * 8;
  const ushort* Wg0 = W + (size_t)(n0 + r0) * D_MODEL + gc * 8;
  const ushort* Wg1 = W + (size_t)(n0 + r0 + 64) * D_MODEL + gc * 8;

  const int sw = (quad ^ (l15 >> 2) ^ l15) & 3;

  f32x4 acc[4][4];
#pragma unroll
  for (int i = 0; i < 4; ++i)
#pragma unroll
    for (int j = 0; j < 4; ++j) acc[i][j] = (f32x4){0.f, 0.f, 0.f, 0.f};

  for (int kt = 0; kt < D_MODEL / 32; ++kt) {
    if (kt) __syncthreads();
    GLLDS16(Ag0 + kt * 32, &As[(size_t)tid * 8]);
    GLLDS16(Ag1 + kt * 32, &As[(size_t)(tid + 256) * 8]);
    GLLDS16(Wg0 + kt * 32, &Bs[(size_t)tid * 8]);
    GLLDS16(Wg1 + kt * 32, &Bs[(size_t)(tid + 256) * 8]);
    __syncthreads();  // compiler drains vmcnt before barrier

    bf16x8 af[4], bfr[4];
#pragma unroll
    for (int mt = 0; mt < 4; ++mt) {
      int row = wy * 64 + mt * 16 + l15;
      af[mt] = *(const bf16x8*)&As[(row * 4 + sw) * 8];
    }
#pragma unroll
    for (int nt = 0; nt < 4; ++nt) {
      int row = wx * 64 + nt * 16 + l15;
      bfr[nt] = *(const bf16x8*)&Bs[(row * 4 + sw) * 8];
    }
#pragma unroll
    for (int mt = 0; mt < 4; ++mt)
#pragma unroll
      for (int nt = 0; nt < 4; ++nt)
        acc[mt][nt] = __builtin_amdgcn_mfma_f32_16x16x32_bf16(
            af[mt], bfr[nt], acc[mt][nt], 0, 0, 0);
  }

  // ---- epilogue. C/D: row = quad*4+r, col = l15 per 16x16 tile.
  const float qsc = (z == 0) ? QSCALE : 1.0f;
#pragma unroll
  for (int mt = 0; mt < 4; ++mt) {
    int m_base = m0 + wy * 64 + mt * 16 + quad * 4;
    int b = m_base >> 11, s_base = m_base & (SEQ - 1);
#pragma unroll
    for (int nt = 0; nt < 4; ++nt) {
      int n = n0 + wx * 64 + nt * 16 + l15;
      if (mode == 0) {
#pragma unroll
        for (int r = 0; r < 4; ++r)
          outF[(size_t)(m_base + r) * D_MODEL + n] = acc[mt][nt][r];
      } else {
        int h = n >> 6, dh = n & 63;
        if (z == 2) {  // V: transposed + key-permuted columns (see header)
          int p_base = (s_base & ~31) | (((s_base >> 2) & 3) << 3) |
                       (((s_base >> 4) & 1) << 2);
          ushort4 o;
          o.x = f2b(acc[mt][nt][0]); o.y = f2b(acc[mt][nt][1]);
          o.z = f2b(acc[mt][nt][2]); o.w = f2b(acc[mt][nt][3]);
          *(ushort4*)&outB[((size_t)(b * NHEAD + h) * DHEAD + dh) * SEQ + p_base] = o;
        } else {       // Q/K: RoPE via table, pair partner via lane shuffle
          int i = nt * 8 + (l15 >> 1);   // freq index, pair-uniform
          bool evn = !(l15 & 1);
#pragma unroll
          for (int r = 0; r < 4; ++r) {
            float v = acc[mt][nt][r];
            float pv = __shfl_xor(v, 1);
            float2 csn = tbl[(s_base + r) * 32 + i];
            v = v * csn.x + (evn ? -pv * csn.y : pv * csn.y);
            v *= qsc;
            outB[(((size_t)(b * NHEAD + h)) * SEQ + s_base + r) * DHEAD + dh] = f2b(v);
          }
        }
      }
    }
  }
}

// ---------------------------------------------------------------------------
// bf16 MFMA causal flash attention -- S^T operand-swap form (P LDS round-trip
// ELIMINATED). S^T = K.Q^T via mfma(A=K, B=Q): C-layout puts qrow in l15 and
// keys in quad*4+r, which is exactly B-operand orientation for
// O^T = V^T.P^T: exp2'd probabilities are packed to bf16 IN REGISTERS and fed
// straight into the PV MFMA. The k-slot ordering (slot q*8+j <-> key
// j<4 ? 4q+j : 16+4q+j-4) is baked into the global Vt column permutation by
// the QKV gemm, so V A-frag reads are plain swizzled ds_read_b128.
// Per wave-ktile LDS: 16 b128 reads + 4 b128 writes (was 18R+4W+16 b16 W).
// LDS 16KB (no Ps). Register-prefetch staging (R8/R9 win), unpadded XOR
// geometry (R9: conflicts=0). Row sums: per-lane scalar (lane=qrow), 2
// shuffles at the end. Heads 8-15 walk qt reversed for CU balance.
// ---------------------------------------------------------------------------
__global__ __launch_bounds__(256)
void flash_mfma(const ushort* __restrict__ Q, const ushort* __restrict__ K,
                const ushort* __restrict__ Vt, ushort* __restrict__ O) {
  __shared__ ushort Ks[64 * 64];     // [key][dh], chunk-swizzled
  __shared__ ushort Vs[64 * 64];     // [dh][keypos], chunk-swizzled
  const int tid = threadIdx.x;
  const int lane = tid & 63, w = tid >> 6;
  const int quad = lane >> 4, l15 = lane & 15;
  const int h = blockIdx.y, b = blockIdx.z;
  const int qt = (h >= 8) ? (31 - blockIdx.x) : blockIdx.x;
  const int bh = b * NHEAD + h;

  // Q as B-operand (B frag layout == A frag layout): lane n=l15=qrow
  const int qrow = qt * 64 + w * 16 + l15;
  const ushort* Qrow = Q + ((size_t)bh * SEQ + qrow) * 64;
  bf16x8 aq0 = *(const bf16x8*)(Qrow + quad * 8);
  bf16x8 aq1 = *(const bf16x8*)(Qrow + 32 + quad * 8);

  // staging: thread owns rows rl and rl+32, LDS slot tid&7, global chunk XOR'd
  const int rl = tid >> 3;
  const int gsc = (tid & 7) ^ (rl & 7);  // (rl+32)&7 == rl&7
  const ushort* Kg0 = K + ((size_t)bh * SEQ + rl) * 64 + gsc * 8;
  const ushort* Kg1 = Kg0 + (size_t)32 * 64;
  const ushort* Vg0 = Vt + ((size_t)bh * 64 + rl) * SEQ + gsc * 8;
  const ushort* Vg1 = Vg0 + (size_t)32 * SEQ;

  // reader chunk slots (slot quad^(r&7) holds chunk quad; frag rows r&7==l15&7)
  const int sA = (quad ^ (l15 & 7)) * 8;  // dh/keypos 0..31
  const int sB = sA ^ 32;                 // dh/keypos 32..63

  float rsl = 0.f;       // per-lane row sum (lane's qrow)
  f32x4 accO[4];         // O^T dh-tiles: row=dh quad*4+r, col=l15=qrow
#pragma unroll
  for (int nt = 0; nt < 4; ++nt) accO[nt] = (f32x4){0.f, 0.f, 0.f, 0.f};

  float4 pk0 = *(const float4*)(Kg0);
  float4 pk1 = *(const float4*)(Kg1);
  float4 pv0 = *(const float4*)(Vg0);
  float4 pv1 = *(const float4*)(Vg1);

  for (int kt = 0; kt <= qt; ++kt) {
    __syncthreads();  // prior iter's LDS reads complete
    *(float4*)&Ks[tid * 8]        = pk0;
    *(float4*)&Ks[2048 + tid * 8] = pk1;
    *(float4*)&Vs[tid * 8]        = pv0;
    *(float4*)&Vs[2048 + tid * 8] = pv1;
    __syncthreads();
    if (kt < qt) {  // prefetch kt+1 into registers; overlaps all compute below
      pk0 = *(const float4*)(Kg0 + (size_t)(kt + 1) * 64 * 64);
      pk1 = *(const float4*)(Kg1 + (size_t)(kt + 1) * 64 * 64);
      pv0 = *(const float4*)(Vg0 + (kt + 1) * 64);
      pv1 = *(const float4*)(Vg1 + (kt + 1) * 64);
    }

    // ---- S^T = K . Q^T : C-tile nt holds keys nt*16+quad*4+r, qrow=l15
    f32x4 sc[4];
#pragma unroll
    for (int nt = 0; nt < 4; ++nt) {
      const ushort* kr = &Ks[(nt * 16 + l15) * 64];
      bf16x8 bk0 = *(const bf16x8*)(kr + sA);
      bf16x8 bk1 = *(const bf16x8*)(kr + sB);
      f32x4 zz = (f32x4){0.f, 0.f, 0.f, 0.f};
      zz = __builtin_amdgcn_mfma_f32_16x16x32_bf16(bk0, aq0, zz, 0, 0, 0);
      zz = __builtin_amdgcn_mfma_f32_16x16x32_bf16(bk1, aq1, zz, 0, 0, 0);
      sc[nt] = zz;
    }

    // ---- exp2 + causal mask + row-sum + pack P^T B-frags in registers
    const bool diag = (kt == qt);
    uint pk[8];
#pragma unroll
    for (int nt = 0; nt < 4; ++nt) {
      int kbase = kt * 64 + nt * 16 + quad * 4;
      ushort us[4];
#pragma unroll
      for (int r = 0; r < 4; ++r) {
        float p = __builtin_amdgcn_exp2f(sc[nt][r]);
        if (diag && kbase + r > qrow) p = 0.f;
        rsl += p;
        us[r] = f2b(p);
      }
      pk[nt * 2]     = (uint)us[0] | ((uint)us[1] << 16);
      pk[nt * 2 + 1] = (uint)us[2] | ((uint)us[3] << 16);
    }
    union { uint u[4]; bf16x8 v; } B0, B1;
    B0.u[0] = pk[0]; B0.u[1] = pk[1]; B0.u[2] = pk[2]; B0.u[3] = pk[3];
    B1.u[0] = pk[4]; B1.u[1] = pk[5]; B1.u[2] = pk[6]; B1.u[3] = pk[7];

    // ---- O^T += V^T . P^T  (A from LDS, B straight from registers)
#pragma unroll
    for (int nt = 0; nt < 4; ++nt) {
      const ushort* vr = &Vs[(nt * 16 + l15) * 64];
      bf16x8 av0 = *(const bf16x8*)(vr + sA);
      bf16x8 av1 = *(const bf16x8*)(vr + sB);
      accO[nt] = __builtin_amdgcn_mfma_f32_16x16x32_bf16(av0, B0.v, accO[nt], 0, 0, 0);
      accO[nt] = __builtin_amdgcn_mfma_f32_16x16x32_bf16(av1, B1.v, accO[nt], 0, 0, 0);
    }
  }

  // ---- row-sum reduction across the 4 quads (lane's qrow fixed = l15)
  rsl += __shfl_xor(rsl, 16);
  rsl += __shfl_xor(rsl, 32);
  float invl = 1.f / rsl;

  // ---- epilogue: attn_out bf16, (B,S,H*Dh); lane writes 4 ushort4 runs
  size_t base = ((size_t)(b * SEQ + qrow)) * D_MODEL + h * 64;
#pragma unroll
  for (int nt = 0; nt < 4; ++nt) {
    ushort4 o;
    o.x = f2b(accO[nt][0] * invl);
    o.y = f2b(accO[nt][1] * invl);
    o.z = f2b(accO[nt][2] * invl);
    o.w = f2b(accO[nt][3] * invl);
    *(ushort4*)&O[base + nt * 16 + quad * 4] = o;
  }
}

// ---------------------------------------------------------------------------
extern "C" void kernel_launch(void* const* d_in, const int* in_sizes, int n_in,
                              void* d_out, int out_size, void* d_ws, size_t ws_size,
                              hipStream_t stream) {
  const float* X  = (const float*)d_in[0];
  const float* Wq = (const float*)d_in[1];
  const float* Wk = (const float*)d_in[2];
  const float* Wv = (const float*)d_in[3];
  const float* Wo = (const float*)d_in[4];
  float* out = (float*)d_out;

  ushort* Xb  = (ushort*)d_ws;
  ushort* Wqb = Xb  + (size_t)MTOT * D_MODEL;
  ushort* Wkb = Wqb + (size_t)D_MODEL * D_MODEL;
  ushort* Wvb = Wkb + (size_t)D_MODEL * D_MODEL;
  ushort* Wob = Wvb + (size_t)D_MODEL * D_MODEL;
  ushort* Qw  = Wob + (size_t)D_MODEL * D_MODEL;
  ushort* Kw  = Qw  + (size_t)MTOT * D_MODEL;
  ushort* Vtw = Kw  + (size_t)MTOT * D_MODEL;  // (B,H,Dh,S) key-permuted
  ushort* At  = Vtw + (size_t)MTOT * D_MODEL;
  float2* tbl = (float2*)(At + (size_t)MTOT * D_MODEL);  // 512 KB

  prep<<<8448, 256, 0, stream>>>(X, Wq, Wk, Wv, Wo, Xb, Wqb, Wkb, Wvb, Wob, tbl);

  // QKV projection; RoPE fused (table) on Q/K, Q pre-scaled; V transposed+permuted
  gemm_bf16<<<dim3(D_MODEL / 128, MTOT / 128, 3), 256, 0, stream>>>(
      Xb, Wqb, Wkb, Wvb, tbl, nullptr, Qw, Kw, Vtw, 1);

  flash_mfma<<<dim3(SEQ / 64, NHEAD, BATCH), 256, 0, stream>>>(Qw, Kw, Vtw, At);

  gemm_bf16<<<dim3(D_MODEL / 128, MTOT / 128, 1), 256, 0, stream>>>(
      At, Wob, nullptr, nullptr, tbl, out, nullptr, nullptr, nullptr, 0);
}